// Round 1
// baseline (14197.746 us; speedup 1.0000x reference)
//
#include <hip/hip_runtime.h>
#include <math.h>

// ============================================================================
// EncoderDecoder (LSTM seq2seq + Luong attention + greedy decode), fp32.
// Round 0: correctness-first multi-kernel implementation.
//   - Encoder: XW = emb[source]@Wih^T + bias precomputed per 64-step chunk
//     (k_gemm), then 256x k_enc_step for the h@Whh^T recurrence (h ping-pong
//     buffers to avoid cross-block RAW races between steps).
//   - hsW = hs@W_a via k_gemm (stored [b][l][k] for attention streaming).
//   - Decoder: 32x { k_dec_step (LSTM), k_dec_attn (scores/softmax/ctx),
//     k_attg (att = tanh([ctx,hd]@W_c+b_c)), k_logits (att@oWT + out_b,
//     writes d_out + per-block argmax partials), k_argmax (-> Y feedback) }.
// All math fp32 with expf/tanhf to track the numpy reference closely
// (argmax feedback makes precision deviations catastrophic, not gradual).
// Future rounds: split-bf16 MFMA for the GEMMs, fewer launches (persistent /
// cooperative encoder), D2 L-split to fix per-CU L2 BW bound.
// ============================================================================

#define H   512
#define B   64
#define L   256
#define V   32000
#define NG  2048   // 4*H
#define TDEC 32

__device__ __forceinline__ float sigf(float x){ return 1.0f/(1.0f + expf(-x)); }

// ---------------------------------------------------------------------------
// init: zero h0/c0, bias sums, Y=BOS
__global__ __launch_bounds__(256) void k_init(
    const float* bih_e, const float* bhh_e, const float* bih_d, const float* bhh_d,
    float* hA, float* cT, float* h_n, float* bsE, float* bsD, int* Y)
{
  int i = blockIdx.x*256 + threadIdx.x;
  if (i < H*B){ hA[i] = 0.0f; cT[i] = 0.0f; h_n[i] = 0.0f; }
  if (i < NG){ bsE[i] = bih_e[i] + bhh_e[i]; bsD[i] = bih_d[i] + bhh_d[i]; }
  if (i < B) Y[i] = 1;  // BOS
}

// ---------------------------------------------------------------------------
// tiled transpose: out[c][r] = in[r][c]; in is R x C. grid (C/32, R/32)
__global__ __launch_bounds__(256) void k_transpose(const float* in, float* out, int R, int C)
{
  __shared__ float tile[32][33];
  int tx = threadIdx.x & 31, ty = threadIdx.x >> 5;
  int r0 = blockIdx.y*32, c0 = blockIdx.x*32;
  #pragma unroll
  for (int i=0;i<4;i++)
    tile[ty + i*8][tx] = in[(size_t)(r0 + ty + i*8)*C + c0 + tx];
  __syncthreads();
  #pragma unroll
  for (int i=0;i<4;i++)
    out[(size_t)(c0 + ty + i*8)*R + r0 + tx] = tile[tx][ty + i*8];
}

// ---------------------------------------------------------------------------
// C[m][n] = bias[n] + sum_k A_row(m)[k]*Bt[k][n]
// A_row(m): gather ? gather[m] : (swapLB ? (m&63)*256+(m>>6) : m)   (row of A, stride K)
// C row index gets the same swapLB mapping (used to store hsW as [b][l][k]).
// Block: 128x128 tile, 256 threads, 8x8 per thread, K staged in chunks of 16.
__global__ __launch_bounds__(256) void k_gemm(
    const float* A, const float* Bt, const float* bias, const int* gather,
    float* Cout, int M, int N, int K, int swapLB)
{
  __shared__ float As[16][132];
  __shared__ float Bs[16][132];
  int tid = threadIdx.x;
  int m0 = blockIdx.x*128, n0 = blockIdx.y*128;
  int mt = tid >> 4, nt = tid & 15;
  float acc[8][8] = {};

  int sa_m = tid >> 1;
  int sa_k = (tid & 1) * 8;
  int sb_k = tid >> 4;
  int sb_n = (tid & 15) * 8;

  int am = m0 + sa_m;
  int arow = swapLB ? (((am & 63) << 8) | (am >> 6)) : am;
  if (gather) arow = gather[am];
  const float* Ar = A + (size_t)arow * K;

  for (int k0 = 0; k0 < K; k0 += 16){
    float4 a0 = *(const float4*)(Ar + k0 + sa_k);
    float4 a1 = *(const float4*)(Ar + k0 + sa_k + 4);
    const float* Bp = Bt + (size_t)(k0 + sb_k)*N + n0 + sb_n;
    float4 b0 = *(const float4*)(Bp);
    float4 b1 = *(const float4*)(Bp + 4);
    __syncthreads();
    As[sa_k+0][sa_m]=a0.x; As[sa_k+1][sa_m]=a0.y; As[sa_k+2][sa_m]=a0.z; As[sa_k+3][sa_m]=a0.w;
    As[sa_k+4][sa_m]=a1.x; As[sa_k+5][sa_m]=a1.y; As[sa_k+6][sa_m]=a1.z; As[sa_k+7][sa_m]=a1.w;
    *(float4*)&Bs[sb_k][sb_n]   = b0;
    *(float4*)&Bs[sb_k][sb_n+4] = b1;
    __syncthreads();
    #pragma unroll
    for (int kk=0; kk<16; kk++){
      float a8[8], b8[8];
      *(float4*)&a8[0] = *(const float4*)&As[kk][mt*8];
      *(float4*)&a8[4] = *(const float4*)&As[kk][mt*8+4];
      *(float4*)&b8[0] = *(const float4*)&Bs[kk][nt*8];
      *(float4*)&b8[4] = *(const float4*)&Bs[kk][nt*8+4];
      #pragma unroll
      for (int i=0;i<8;i++)
        #pragma unroll
        for (int j=0;j<8;j++)
          acc[i][j] = fmaf(a8[i], b8[j], acc[i][j]);
    }
  }

  float bv[8];
  #pragma unroll
  for (int j=0;j<8;j++) bv[j] = bias ? bias[n0 + nt*8 + j] : 0.0f;
  #pragma unroll
  for (int i=0;i<8;i++){
    int m = m0 + mt*8 + i;
    size_t crow = swapLB ? (size_t)(((m & 63) << 8) | (m >> 6)) : (size_t)m;
    float* cp = Cout + crow*(size_t)N + n0 + nt*8;
    float4 o0, o1;
    o0.x=acc[i][0]+bv[0]; o0.y=acc[i][1]+bv[1]; o0.z=acc[i][2]+bv[2]; o0.w=acc[i][3]+bv[3];
    o1.x=acc[i][4]+bv[4]; o1.y=acc[i][5]+bv[5]; o1.z=acc[i][6]+bv[6]; o1.w=acc[i][7]+bv[7];
    *(float4*)cp = o0; *(float4*)(cp+4) = o1;
  }
}

// ---------------------------------------------------------------------------
// One encoder step: gates = XWc[l_loc] + h@Whh^T ; LSTM update with pack mask.
// grid 256 blocks (2 hidden idx each), 256 threads: p=t>>5 selects one of 8
// gate rows (4 gates x 2 jj), (t&31)*2 selects batch pair.
// h in/out are distinct buffers (ping-pong) -> no cross-block races.
__global__ __launch_bounds__(256) void k_enc_step(
    const float* XWc, int l_loc, int l, const float* Whh,
    const float* hin, float* hout, float* cT, float* h_n, float* hs, const int* source)
{
  int t = threadIdx.x;
  int jj0 = blockIdx.x * 2;
  int p = t >> 5;
  int b2 = (t & 31) * 2;
  int g = p >> 1, jq = p & 1;
  int j = g*512 + (jj0 + jq);
  const float* wr = Whh + (size_t)j * H;
  float acc0 = XWc[((size_t)l_loc*64 + b2    )*NG + j];
  float acc1 = XWc[((size_t)l_loc*64 + b2 + 1)*NG + j];
  for (int k=0;k<H;k+=4){
    float4 w = *(const float4*)(wr + k);
    float2 h0 = *(const float2*)(hin + (size_t)(k+0)*B + b2);
    float2 h1 = *(const float2*)(hin + (size_t)(k+1)*B + b2);
    float2 h2 = *(const float2*)(hin + (size_t)(k+2)*B + b2);
    float2 h3 = *(const float2*)(hin + (size_t)(k+3)*B + b2);
    acc0 = fmaf(h0.x,w.x,acc0); acc1 = fmaf(h0.y,w.x,acc1);
    acc0 = fmaf(h1.x,w.y,acc0); acc1 = fmaf(h1.y,w.y,acc1);
    acc0 = fmaf(h2.x,w.z,acc0); acc1 = fmaf(h2.y,w.z,acc1);
    acc0 = fmaf(h3.x,w.w,acc0); acc1 = fmaf(h3.y,w.w,acc1);
  }
  __shared__ float gl[8][64];
  gl[p][b2] = acc0; gl[p][b2+1] = acc1;
  __syncthreads();
  if (t < 128){
    int b = t & 63, q = t >> 6;
    int jj = jj0 + q;
    float iv = sigf (gl[0+q][b]);
    float fv = sigf (gl[2+q][b]);
    float gv = tanhf(gl[4+q][b]);
    float ov = sigf (gl[6+q][b]);
    float c_old = cT[(size_t)jj*B + b];
    float cn = fmaf(fv, c_old, iv*gv);
    float hn = ov * tanhf(cn);
    bool msk = source[(size_t)l*B + b] > 0;
    float h_old = hin[(size_t)jj*B + b];
    float ho = msk ? hn : h_old;
    float co = msk ? cn : c_old;
    hout[(size_t)jj*B + b] = ho;
    cT  [(size_t)jj*B + b] = co;
    h_n [(size_t)b*H + jj] = ho;
    hs[((size_t)b*L + l)*H + jj] = msk ? hn : 0.0f;   // hs stored [b][l][k]
  }
}

// ---------------------------------------------------------------------------
// One decoder LSTM step: gates = bsum + emb[Y[b]]@Wih^T + h@Whh^T ; update.
__global__ __launch_bounds__(256) void k_dec_step(
    const float* dec_emb, const int* Y, const float* Wih, const float* Whh,
    const float* bsum, const float* hin, float* hout, float* cT, float* h_n)
{
  int t = threadIdx.x;
  int jj0 = blockIdx.x * 2;
  int p = t >> 5;
  int b2 = (t & 31) * 2;
  int g = p >> 1, jq = p & 1;
  int j = g*512 + (jj0 + jq);
  const float* wi = Wih + (size_t)j * H;
  const float* wr = Whh + (size_t)j * H;
  const float* e0 = dec_emb + (size_t)Y[b2]  * H;
  const float* e1 = dec_emb + (size_t)Y[b2+1]* H;
  float acc0 = bsum[j], acc1 = bsum[j];
  for (int k=0;k<H;k+=4){
    float4 w  = *(const float4*)(wi + k);
    float4 x0 = *(const float4*)(e0 + k);
    float4 x1 = *(const float4*)(e1 + k);
    acc0 = fmaf(x0.x,w.x,acc0); acc0 = fmaf(x0.y,w.y,acc0);
    acc0 = fmaf(x0.z,w.z,acc0); acc0 = fmaf(x0.w,w.w,acc0);
    acc1 = fmaf(x1.x,w.x,acc1); acc1 = fmaf(x1.y,w.y,acc1);
    acc1 = fmaf(x1.z,w.z,acc1); acc1 = fmaf(x1.w,w.w,acc1);
  }
  for (int k=0;k<H;k+=4){
    float4 w = *(const float4*)(wr + k);
    float2 h0 = *(const float2*)(hin + (size_t)(k+0)*B + b2);
    float2 h1 = *(const float2*)(hin + (size_t)(k+1)*B + b2);
    float2 h2 = *(const float2*)(hin + (size_t)(k+2)*B + b2);
    float2 h3 = *(const float2*)(hin + (size_t)(k+3)*B + b2);
    acc0 = fmaf(h0.x,w.x,acc0); acc1 = fmaf(h0.y,w.x,acc1);
    acc0 = fmaf(h1.x,w.y,acc0); acc1 = fmaf(h1.y,w.y,acc1);
    acc0 = fmaf(h2.x,w.z,acc0); acc1 = fmaf(h2.y,w.z,acc1);
    acc0 = fmaf(h3.x,w.w,acc0); acc1 = fmaf(h3.y,w.w,acc1);
  }
  __shared__ float gl[8][64];
  gl[p][b2] = acc0; gl[p][b2+1] = acc1;
  __syncthreads();
  if (t < 128){
    int b = t & 63, q = t >> 6;
    int jj = jj0 + q;
    float iv = sigf (gl[0+q][b]);
    float fv = sigf (gl[2+q][b]);
    float gv = tanhf(gl[4+q][b]);
    float ov = sigf (gl[6+q][b]);
    float c_old = cT[(size_t)jj*B + b];
    float cn = fmaf(fv, c_old, iv*gv);
    float hn = ov * tanhf(cn);
    hout[(size_t)jj*B + b] = hn;
    cT  [(size_t)jj*B + b] = cn;
    h_n [(size_t)b*H + jj] = hn;
  }
}

// ---------------------------------------------------------------------------
// Attention: scores -> softmax(masked) -> ctx. One block per batch b.
__global__ __launch_bounds__(256) void k_dec_attn(
    const float* h_n, const float* hsW, const float* hs, const int* source, float* ctxT)
{
  int b = blockIdx.x, t = threadIdx.x;
  __shared__ float hd_s[H];
  __shared__ float sc[L];
  __shared__ float red[128];
  if (t < 128) *(float4*)&hd_s[t*4] = *(const float4*)(h_n + (size_t)b*H + t*4);
  __syncthreads();
  // score[t] = hd . hsW[b][t][:]
  const float* row = hsW + ((size_t)b*L + t)*H;
  float s = 0.0f;
  for (int k=0;k<H;k+=4){
    float4 hv = *(const float4*)&hd_s[k];
    float4 wv = *(const float4*)(row + k);
    s = fmaf(hv.x,wv.x,s); s = fmaf(hv.y,wv.y,s);
    s = fmaf(hv.z,wv.z,s); s = fmaf(hv.w,wv.w,s);
  }
  sc[t] = s;
  __syncthreads();
  if (t < 128) red[t] = fmaxf(sc[t], sc[t+128]);
  __syncthreads();
  for (int st=64; st>0; st>>=1){
    if (t < st) red[t] = fmaxf(red[t], red[t+st]);
    __syncthreads();
  }
  float mx = red[0];
  float e = expf(s - mx) * ((source[(size_t)t*B + b] > 0) ? 1.0f : 0.0f);
  sc[t] = e;
  __syncthreads();
  if (t < 128) red[t] = sc[t] + sc[t+128];
  __syncthreads();
  for (int st=64; st>0; st>>=1){
    if (t < st) red[t] += red[t+st];
    __syncthreads();
  }
  float sumv = red[0];
  sc[t] = sc[t] / sumv;    // a[l], per-element divide matches reference
  __syncthreads();
  // ctx[k] = sum_l a[l]*hs[b][l][k]; thread covers k = 2t, 2t+1
  const float* hsb = hs + (size_t)b*L*H;
  float c0 = 0.0f, c1 = 0.0f;
  for (int li=0; li<L; li++){
    float a = sc[li];
    float2 v = *(const float2*)(hsb + (size_t)li*H + t*2);
    c0 = fmaf(a, v.x, c0);
    c1 = fmaf(a, v.y, c1);
  }
  ctxT[(size_t)(t*2  )*B + b] = c0;
  ctxT[(size_t)(t*2+1)*B + b] = c1;
}

// ---------------------------------------------------------------------------
// att = tanh([ctx, hd] @ W_c + b_c). grid 128 x 256thr: j = bid*4 + (t>>6).
__global__ __launch_bounds__(256) void k_attg(
    const float* ctxT, const float* hdT, const float* W_c, const float* b_c, float* attT)
{
  int t = threadIdx.x;
  int b = t & 63;
  int j = blockIdx.x*4 + (t >> 6);
  float acc = b_c[j];
  for (int k=0;k<H;k++)
    acc = fmaf(ctxT[(size_t)k*B + b], W_c[(size_t)k*H + j], acc);
  for (int k=0;k<H;k++)
    acc = fmaf(hdT[(size_t)k*B + b], W_c[(size_t)(H+k)*H + j], acc);
  attT[(size_t)j*B + b] = tanhf(acc);
}

// ---------------------------------------------------------------------------
// logits[b][v] = out_b[v] + att[b] . oWT[:,v]; writes d_out slice; per-block
// argmax partials (first-index tie-break). Block: 128 v x all 64 b.
__global__ __launch_bounds__(256) void k_logits(
    const float* attT, const float* oWT, const float* out_b,
    float* outp, float* gmax, int* gidx)
{
  int t = threadIdx.x;
  int vq = t & 31, bo = t >> 5;           // 32 v-quads (128 v), 8 b-octets (64 b)
  int v0 = blockIdx.x * 128;
  __shared__ float att_s[128*64];         // one K-chunk of att_T (contiguous copy)
  __shared__ float rv[64][33];
  __shared__ int   ri[64][33];

  float acc[8][4];
  float4 bias = *(const float4*)(out_b + v0 + vq*4);
  #pragma unroll
  for (int i=0;i<8;i++){ acc[i][0]=bias.x; acc[i][1]=bias.y; acc[i][2]=bias.z; acc[i][3]=bias.w; }

  for (int k0=0; k0<H; k0+=128){
    __syncthreads();
    const float4* src = (const float4*)(attT + (size_t)k0*B);
    float4* dst = (float4*)att_s;
    #pragma unroll
    for (int i=0;i<8;i++) dst[i*256 + t] = src[i*256 + t];
    __syncthreads();
    for (int kk=0; kk<128; kk++){
      float4 w = *(const float4*)(oWT + (size_t)(k0+kk)*V + v0 + vq*4);
      float a8[8];
      *(float4*)&a8[0] = *(const float4*)&att_s[kk*64 + bo*8];
      *(float4*)&a8[4] = *(const float4*)&att_s[kk*64 + bo*8 + 4];
      #pragma unroll
      for (int i=0;i<8;i++){
        acc[i][0] = fmaf(a8[i], w.x, acc[i][0]);
        acc[i][1] = fmaf(a8[i], w.y, acc[i][1]);
        acc[i][2] = fmaf(a8[i], w.z, acc[i][2]);
        acc[i][3] = fmaf(a8[i], w.w, acc[i][3]);
      }
    }
  }
  // write logits + per-thread argmax over its 4 consecutive v (ascending, strict >)
  #pragma unroll
  for (int i=0;i<8;i++){
    int b = bo*8 + i;
    float4 o; o.x=acc[i][0]; o.y=acc[i][1]; o.z=acc[i][2]; o.w=acc[i][3];
    *(float4*)(outp + (size_t)b*V + v0 + vq*4) = o;
    float mv = acc[i][0]; int mi = v0 + vq*4;
    #pragma unroll
    for (int jx=1;jx<4;jx++)
      if (acc[i][jx] > mv){ mv = acc[i][jx]; mi = v0 + vq*4 + jx; }
    rv[b][vq] = mv; ri[b][vq] = mi;
  }
  __syncthreads();
  if (t < 64){
    float mv = rv[t][0]; int mi = ri[t][0];
    for (int q=1;q<32;q++)                 // ascending v order -> strict > keeps first
      if (rv[t][q] > mv){ mv = rv[t][q]; mi = ri[t][q]; }
    gmax[(size_t)blockIdx.x*64 + t] = mv;
    gidx[(size_t)blockIdx.x*64 + t] = mi;
  }
}

// ---------------------------------------------------------------------------
__global__ void k_argmax(const float* gmax, const int* gidx, int* Y)
{
  int b = threadIdx.x;  // 64 threads
  float mv = gmax[b]; int mi = gidx[b];
  for (int blk=1; blk<250; blk++){         // ascending v-chunk order
    float v = gmax[(size_t)blk*64 + b];
    if (v > mv){ mv = v; mi = gidx[(size_t)blk*64 + b]; }
  }
  Y[b] = mi;
}

// ===========================================================================
extern "C" void kernel_launch(void* const* d_in, const int* in_sizes, int n_in,
                              void* d_out, int out_size, void* d_ws, size_t ws_size,
                              hipStream_t stream)
{
  const int*   source  = (const int*)  d_in[0];
  const float* enc_emb = (const float*)d_in[1];
  const float* enc_Wih = (const float*)d_in[2];
  const float* enc_Whh = (const float*)d_in[3];
  const float* enc_bih = (const float*)d_in[4];
  const float* enc_bhh = (const float*)d_in[5];
  const float* dec_emb = (const float*)d_in[6];
  const float* dec_Wih = (const float*)d_in[7];
  const float* dec_Whh = (const float*)d_in[8];
  const float* dec_bih = (const float*)d_in[9];
  const float* dec_bhh = (const float*)d_in[10];
  const float* W_a     = (const float*)d_in[11];
  const float* W_c     = (const float*)d_in[12];
  const float* b_c     = (const float*)d_in[13];
  const float* out_W   = (const float*)d_in[14];
  const float* out_b   = (const float*)d_in[15];
  float* out = (float*)d_out;

  float* ws = (float*)d_ws;
  size_t o = 0;
  float* XWc  = ws + o; o += (size_t)4096*NG;        // 64-step chunk of x@Wih^T + bias
  float* hs   = ws + o; o += (size_t)B*L*H;          // [b][l][k]
  float* hsW  = ws + o; o += (size_t)B*L*H;          // [b][l][k]
  float* WihT = ws + o; o += (size_t)H*NG;
  float* oWT  = ws + o; o += (size_t)H*V;
  float* hA   = ws + o; o += (size_t)H*B;            // h_T ping
  float* hB   = ws + o; o += (size_t)H*B;            // h_T pong
  float* cT   = ws + o; o += (size_t)H*B;
  float* h_n  = ws + o; o += (size_t)B*H;            // h in [b][k] layout
  float* bsE  = ws + o; o += NG;
  float* bsD  = ws + o; o += NG;
  float* ctxT = ws + o; o += (size_t)H*B;
  float* attT = ws + o; o += (size_t)H*B;
  float* gmax = ws + o; o += (size_t)250*64;
  int*   gidx = (int*)(ws + o); o += (size_t)250*64;
  int*   Y    = (int*)(ws + o); o += 64;
  (void)ws_size; (void)in_sizes; (void)n_in; (void)out_size;

  k_init<<<128,256,0,stream>>>(enc_bih, enc_bhh, dec_bih, dec_bhh, hA, cT, h_n, bsE, bsD, Y);
  k_transpose<<<dim3(16,64),  256,0,stream>>>(enc_Wih, WihT, NG, H);
  k_transpose<<<dim3(16,1000),256,0,stream>>>(out_W,   oWT,  V,  H);

  float* hbuf[2] = {hA, hB};
  int cur = 0;

  // -------- encoder --------
  for (int c=0;c<4;c++){
    k_gemm<<<dim3(32,16),256,0,stream>>>(enc_emb, WihT, bsE, source + c*4096,
                                         XWc, 4096, NG, H, 0);
    for (int li=0; li<64; li++){
      int l = c*64 + li;
      k_enc_step<<<256,256,0,stream>>>(XWc, li, l, enc_Whh,
                                       hbuf[cur], hbuf[cur^1], cT, h_n, hs, source);
      cur ^= 1;
    }
  }

  // hsW = hs @ W_a, stored [b][l][k]
  k_gemm<<<dim3(128,4),256,0,stream>>>(hs, W_a, nullptr, nullptr,
                                       hsW, L*B, H, H, 1);

  // -------- decoder --------
  for (int t=0;t<TDEC;t++){
    k_dec_step<<<256,256,0,stream>>>(dec_emb, Y, dec_Wih, dec_Whh, bsD,
                                     hbuf[cur], hbuf[cur^1], cT, h_n);
    cur ^= 1;
    k_dec_attn<<<64,256,0,stream>>>(h_n, hsW, hs, source, ctxT);
    k_attg<<<128,256,0,stream>>>(ctxT, hbuf[cur], W_c, b_c, attT);
    k_logits<<<250,256,0,stream>>>(attT, oWT, out_b,
                                   out + (size_t)t*B*V, gmax, gidx);
    k_argmax<<<1,64,0,stream>>>(gmax, gidx, Y);
  }
}